// Round 1
// baseline (1163.889 us; speedup 1.0000x reference)
//
#include <hip/hip_runtime.h>

#define HID 32
#define DLAT 97
#define NPG 100
#define TOPK 30

// ---------------- helpers ----------------

__global__ void zero_f(float* p, int n) {
    int i = blockIdx.x * blockDim.x + threadIdx.x;
    if (i < n) p[i] = 0.f;
}

// deg[dst] += ew  (self-loop +1 added in dinv_kernel)
__global__ void deg_kernel(const int* __restrict__ dst, const float* __restrict__ ew,
                           float* __restrict__ deg, int E) {
    int e = blockIdx.x * blockDim.x + threadIdx.x;
    if (e < E) atomicAdd(&deg[dst[e]], ew[e]);
}

__global__ void dinv_kernel(float* __restrict__ deg, int N) {
    int n = blockIdx.x * blockDim.x + threadIdx.x;
    if (n < N) deg[n] = 1.0f / sqrtf(deg[n] + 1.0f);
}

// norm[e] = dinv[src]*ew*dinv[dst] — shared by all 4 GCN layers
__global__ void norm_kernel(const int* __restrict__ src, const int* __restrict__ dst,
                            const float* __restrict__ ew, const float* __restrict__ dinv,
                            float* __restrict__ norm, int E) {
    int e = blockIdx.x * blockDim.x + threadIdx.x;
    if (e < E) norm[e] = dinv[src[e]] * ew[e] * dinv[dst[e]];
}

// x0[n][f] = z_emb[z[n]][f]
__global__ void emb_kernel(const int* __restrict__ z, const float* __restrict__ z_emb,
                           float* __restrict__ x0, int N) {
    int tid = blockIdx.x * blockDim.x + threadIdx.x;
    if (tid >= N * HID) return;
    int n = tid >> 5, f = tid & 31;
    x0[tid] = z_emb[z[n] * HID + f];
}

// xw[n][f] = (in[n] @ W)[f];  acc97[n*97+f] = xw*dinv[n]^2 + b[f]   (self-loop + bias init)
__global__ void xw_init_kernel(const float* __restrict__ in, int istride,
                               const float* __restrict__ W, const float* __restrict__ b,
                               const float* __restrict__ dinv,
                               float* __restrict__ xw, float* __restrict__ acc97, int N) {
    int tid = blockIdx.x * blockDim.x + threadIdx.x;
    if (tid >= N * HID) return;
    int n = tid >> 5, f = tid & 31;
    const float* row = in + (size_t)n * istride;
    float s = 0.f;
#pragma unroll
    for (int k = 0; k < HID; ++k) s += row[k] * W[k * HID + f];
    xw[tid] = s;
    float di = dinv[n];
    acc97[(size_t)n * DLAT + f] = s * di * di + b[f];
}

// acc97[dst*97+f] += norm[e] * xw[src][f]   (thread per (edge,feature))
__global__ void scatter32_kernel(const int* __restrict__ src, const int* __restrict__ dst,
                                 const float* __restrict__ norm, const float* __restrict__ xw,
                                 float* __restrict__ acc97, int E) {
    int tid = blockIdx.x * blockDim.x + threadIdx.x;
    if (tid >= E * HID) return;
    int e = tid >> 5, f = tid & 31;
    int s = src[e], d = dst[e];
    atomicAdd(&acc97[(size_t)d * DLAT + f], norm[e] * xw[s * HID + f]);
}

__global__ void tanh32_kernel(float* __restrict__ acc97, int N) {
    int tid = blockIdx.x * blockDim.x + threadIdx.x;
    if (tid >= N * HID) return;
    int n = tid >> 5, f = tid & 31;
    size_t idx = (size_t)n * DLAT + f;
    acc97[idx] = tanhf(acc97[idx]);
}

// ---- layer 4 (out width 1) ----
__global__ void xw4_init_kernel(const float* __restrict__ in97, const float* __restrict__ W4,
                                const float* __restrict__ b4, const float* __restrict__ dinv,
                                float* __restrict__ xw4, float* __restrict__ concat, int N) {
    int n = blockIdx.x * blockDim.x + threadIdx.x;
    if (n >= N) return;
    float s = 0.f;
#pragma unroll
    for (int k = 0; k < HID; ++k) s += in97[(size_t)n * DLAT + k] * W4[k];
    xw4[n] = s;
    float di = dinv[n];
    concat[(size_t)n * DLAT + 96] = s * di * di + b4[0];
}

__global__ void scatter1_kernel(const int* __restrict__ src, const int* __restrict__ dst,
                                const float* __restrict__ norm, const float* __restrict__ xw4,
                                float* __restrict__ concat, int E) {
    int e = blockIdx.x * blockDim.x + threadIdx.x;
    if (e >= E) return;
    atomicAdd(&concat[(size_t)dst[e] * DLAT + 96], norm[e] * xw4[src[e]]);
}

__global__ void tanh1_kernel(float* __restrict__ concat, int N) {
    int n = blockIdx.x * blockDim.x + threadIdx.x;
    if (n >= N) return;
    size_t idx = (size_t)n * DLAT + 96;
    concat[idx] = tanhf(concat[idx]);
}

// ---- top-k: stable rank (matches jnp.argsort(-v) tie-break: lower index first) ----
__global__ void topk_kernel(const float* __restrict__ concat, int* __restrict__ top_idx) {
    int g = blockIdx.x;
    int tid = threadIdx.x;
    __shared__ float v[NPG];
    if (tid < NPG) v[tid] = concat[(size_t)(g * NPG + tid) * DLAT + 96];
    __syncthreads();
    if (tid < NPG) {
        float vi = v[tid];
        int cnt = 0;
#pragma unroll 4
        for (int j = 0; j < NPG; ++j) {
            float vj = v[j];
            cnt += (vj > vi) || (vj == vi && j < tid);
        }
        if (cnt < TOPK) top_idx[g * TOPK + cnt] = g * NPG + tid;
    }
}

// ---- head: conv1(97->16 per slot) -> maxpool2 -> conv1d(16->32,k5) -> fc(352->128) -> fc(128->1)
__global__ __launch_bounds__(128) void head_kernel(
    const float* __restrict__ concat, const int* __restrict__ top_idx,
    const float* __restrict__ Wc1, const float* __restrict__ bc1,
    const float* __restrict__ Wc2, const float* __restrict__ bc2,
    const float* __restrict__ Wl1, const float* __restrict__ bl1,
    const float* __restrict__ Wl2, const float* __restrict__ bl2,
    float* __restrict__ out) {
    int g = blockIdx.x;
    int tid = threadIdx.x;  // 128 threads
    __shared__ float top[TOPK * DLAT];   // 2910
    __shared__ float y1[16 * TOPK];      // 480
    __shared__ float y2[16 * 15];        // 240
    __shared__ float y3[352];
    __shared__ float r[128];

    for (int idx = tid; idx < TOPK * DLAT; idx += 128) {
        int k = idx / DLAT, d = idx % DLAT;
        int node = top_idx[g * TOPK + k];
        top[idx] = concat[(size_t)node * DLAT + d];
    }
    __syncthreads();

    // conv1: y1[c][k] = relu(dot(top[k], Wc1[c]) + bc1[c]), 16x30
    for (int idx = tid; idx < 16 * TOPK; idx += 128) {
        int c = idx / TOPK, k = idx % TOPK;
        float s = bc1[c];
        const float* w = Wc1 + c * DLAT;
        const float* t = top + k * DLAT;
#pragma unroll 4
        for (int d = 0; d < DLAT; ++d) s += t[d] * w[d];
        y1[c * TOPK + k] = fmaxf(s, 0.f);
    }
    __syncthreads();

    // maxpool(2,2): y2[c][j], 16x15
    for (int idx = tid; idx < 16 * 15; idx += 128) {
        int c = idx / 15, j = idx % 15;
        y2[idx] = fmaxf(y1[c * TOPK + 2 * j], y1[c * TOPK + 2 * j + 1]);
    }
    __syncthreads();

    // conv2: y3[o*11+t] = relu(sum_{i,k} Wc2[o][i][k]*y2[i][t+k] + bc2[o]), 32x11
    for (int idx = tid; idx < 352; idx += 128) {
        int o = idx / 11, t = idx % 11;
        float s = bc2[o];
#pragma unroll
        for (int i = 0; i < 16; ++i) {
#pragma unroll
            for (int k = 0; k < 5; ++k)
                s += Wc2[(o * 16 + i) * 5 + k] * y2[i * 15 + t + k];
        }
        y3[idx] = fmaxf(s, 0.f);
    }
    __syncthreads();

    // fc1 (352->128) + relu, then fold in Wl2 for the final reduction
    {
        float s = bl1[tid];
        for (int d = 0; d < 352; ++d) s += y3[d] * Wl1[d * 128 + tid];
        r[tid] = fmaxf(s, 0.f) * Wl2[tid];
    }
    __syncthreads();
    if (tid < 64) r[tid] += r[tid + 64];
    __syncthreads();
    if (tid == 0) {
        float s = 0.f;
        for (int j = 0; j < 64; ++j) s += r[j];
        out[g] = s + bl2[0];
    }
}

// ---------------- launch ----------------

extern "C" void kernel_launch(void* const* d_in, const int* in_sizes, int n_in,
                              void* d_out, int out_size, void* d_ws, size_t ws_size,
                              hipStream_t stream) {
    const int* z = (const int*)d_in[0];
    const int* ei = (const int*)d_in[1];
    const float* ew = (const float*)d_in[3];
    const float* z_emb = (const float*)d_in[4];
    const float* Wg[4] = {(const float*)d_in[5], (const float*)d_in[7],
                          (const float*)d_in[9], (const float*)d_in[11]};
    const float* bg[4] = {(const float*)d_in[6], (const float*)d_in[8],
                          (const float*)d_in[10], (const float*)d_in[12]};
    const float* Wc1 = (const float*)d_in[13];
    const float* bc1 = (const float*)d_in[14];
    const float* Wc2 = (const float*)d_in[15];
    const float* bc2 = (const float*)d_in[16];
    const float* Wl1 = (const float*)d_in[17];
    const float* bl1 = (const float*)d_in[18];
    const float* Wl2 = (const float*)d_in[19];
    const float* bl2 = (const float*)d_in[20];
    float* out = (float*)d_out;

    const int N = in_sizes[0];
    const int E = in_sizes[1] / 2;
    const int G = out_size;  // 1000 graphs
    const int* src = ei;
    const int* dst = ei + E;

    // workspace layout (floats)
    float* ws = (float*)d_ws;
    float* dinv = ws;                          // N
    float* norm = dinv + N;                    // E
    float* x0 = norm + E;                      // N*32
    float* xw = x0 + (size_t)N * HID;          // N*32 (layer-4 reuses first N)
    float* concat = xw + (size_t)N * HID;      // N*97
    int* top_idx = (int*)(concat + (size_t)N * DLAT);  // G*30

    const int B = 256;
    auto cdiv = [](long long a, long long b) { return (int)((a + b - 1) / b); };

    // degree -> dinv -> norm (shared across layers), embedding
    zero_f<<<cdiv(N, B), B, 0, stream>>>(dinv, N);
    deg_kernel<<<cdiv(E, B), B, 0, stream>>>(dst, ew, dinv, E);
    dinv_kernel<<<cdiv(N, B), B, 0, stream>>>(dinv, N);
    norm_kernel<<<cdiv(E, B), B, 0, stream>>>(src, dst, ew, dinv, norm, E);
    emb_kernel<<<cdiv((long long)N * HID, B), B, 0, stream>>>(z, z_emb, x0, N);

    // GCN layers 1-3 (32-wide), writing tanh output directly into concat columns
    const float* in = x0;
    int istride = HID;
    for (int l = 0; l < 3; ++l) {
        float* acc = concat + l * HID;
        xw_init_kernel<<<cdiv((long long)N * HID, B), B, 0, stream>>>(
            in, istride, Wg[l], bg[l], dinv, xw, acc, N);
        scatter32_kernel<<<cdiv((long long)E * HID, B), B, 0, stream>>>(
            src, dst, norm, xw, acc, E);
        tanh32_kernel<<<cdiv((long long)N * HID, B), B, 0, stream>>>(acc, N);
        in = acc;
        istride = DLAT;
    }

    // layer 4 (width 1) -> concat column 96
    xw4_init_kernel<<<cdiv(N, B), B, 0, stream>>>(concat + 64, Wg[3], bg[3], dinv, xw, concat, N);
    scatter1_kernel<<<cdiv(E, B), B, 0, stream>>>(src, dst, norm, xw, concat, E);
    tanh1_kernel<<<cdiv(N, B), B, 0, stream>>>(concat, N);

    // top-30 selection + CNN/MLP head
    topk_kernel<<<G, 128, 0, stream>>>(concat, top_idx);
    head_kernel<<<G, 128, 0, stream>>>(concat, top_idx, Wc1, bc1, Wc2, bc2,
                                       Wl1, bl1, Wl2, bl2, out);
}

// Round 2
// 789.666 us; speedup vs baseline: 1.4739x; 1.4739x over previous
//
#include <hip/hip_runtime.h>

#define HID 32
#define DLAT 97
#define NPG 100
#define TOPK 30
#define SCAN_B 256

// ---------------- degree / dinv ----------------

__global__ void zero_f(float* p, int n) {
    int i = blockIdx.x * blockDim.x + threadIdx.x;
    if (i < n) p[i] = 0.f;
}

__global__ void zero_i(int* p, int n) {
    int i = blockIdx.x * blockDim.x + threadIdx.x;
    if (i < n) p[i] = 0;
}

// deg[dst] += ew  (self-loop +1 added in dinv_kernel)
__global__ void deg_kernel(const int* __restrict__ dst, const float* __restrict__ ew,
                           float* __restrict__ deg, int E) {
    int e = blockIdx.x * blockDim.x + threadIdx.x;
    if (e < E) atomicAdd(&deg[dst[e]], ew[e]);
}

__global__ void dinv_kernel(float* __restrict__ deg, int N) {
    int n = blockIdx.x * blockDim.x + threadIdx.x;
    if (n < N) deg[n] = 1.0f / sqrtf(deg[n] + 1.0f);
}

// ---------------- CSR build (counting sort by dst) ----------------

__global__ void count_kernel(const int* __restrict__ dst, int* __restrict__ cnt, int E) {
    int e = blockIdx.x * blockDim.x + threadIdx.x;
    if (e < E) atomicAdd(&cnt[dst[e]], 1);
}

// per-block exclusive scan of cnt -> exscan, block totals -> bsum
__global__ void scanA_kernel(const int* __restrict__ cnt, int* __restrict__ exscan,
                             int* __restrict__ bsum, int N) {
    __shared__ int sh[SCAN_B];
    int i = blockIdx.x * SCAN_B + threadIdx.x;
    int v = (i < N) ? cnt[i] : 0;
    sh[threadIdx.x] = v;
    __syncthreads();
    // Hillis-Steele inclusive scan
    for (int off = 1; off < SCAN_B; off <<= 1) {
        int t = (threadIdx.x >= off) ? sh[threadIdx.x - off] : 0;
        __syncthreads();
        sh[threadIdx.x] += t;
        __syncthreads();
    }
    if (i < N) exscan[i] = sh[threadIdx.x] - v;  // exclusive
    if (threadIdx.x == SCAN_B - 1) bsum[blockIdx.x] = sh[threadIdx.x];
}

// single-block exclusive scan of bsum (NB <= 512)
__global__ void scanB_kernel(int* __restrict__ bsum, int NB) {
    __shared__ int sh[512];
    int v = (threadIdx.x < NB) ? bsum[threadIdx.x] : 0;
    sh[threadIdx.x] = v;
    __syncthreads();
    for (int off = 1; off < 512; off <<= 1) {
        int t = (threadIdx.x >= off) ? sh[threadIdx.x - off] : 0;
        __syncthreads();
        sh[threadIdx.x] += t;
        __syncthreads();
    }
    if (threadIdx.x < NB) bsum[threadIdx.x] = sh[threadIdx.x] - v;  // exclusive
}

// row_start = exscan + bsum[block]; cursor = copy; row_start[N] = E
__global__ void scanC_kernel(const int* __restrict__ exscan, const int* __restrict__ bsum,
                             int* __restrict__ row_start, int* __restrict__ cursor,
                             int N, int E) {
    int i = blockIdx.x * SCAN_B + threadIdx.x;
    if (i < N) {
        int v = exscan[i] + bsum[blockIdx.x];
        row_start[i] = v;
        cursor[i] = v;
    }
    if (i == 0) row_start[N] = E;
}

// fill CSR; norm computed inline: dinv[src]*ew*dinv[dst]
__global__ void fill_kernel(const int* __restrict__ src, const int* __restrict__ dst,
                            const float* __restrict__ ew, const float* __restrict__ dinv,
                            int* __restrict__ cursor, int* __restrict__ csr_src,
                            float* __restrict__ csr_norm, int E) {
    int e = blockIdx.x * blockDim.x + threadIdx.x;
    if (e >= E) return;
    int s = src[e], d = dst[e];
    int slot = atomicAdd(&cursor[d], 1);
    csr_src[slot] = s;
    csr_norm[slot] = dinv[s] * ew[e] * dinv[d];
}

// ---------------- GCN layers ----------------

// layer 1: xw[n][f] = dot(z_emb[z[n]], W[:,f])
__global__ void xw1_kernel(const int* __restrict__ z, const float* __restrict__ z_emb,
                           const float* __restrict__ W, float* __restrict__ xw, int N) {
    int tid = blockIdx.x * blockDim.x + threadIdx.x;
    if (tid >= N * HID) return;
    int n = tid >> 5, f = tid & 31;
    const float* row = z_emb + (size_t)z[n] * HID;
    float s = 0.f;
#pragma unroll
    for (int k = 0; k < HID; ++k) s += row[k] * W[k * HID + f];
    xw[tid] = s;
}

// layers 2/3: input rows are concat[n*97 + off .. +32]
__global__ void xwl_kernel(const float* __restrict__ concat, int off,
                           const float* __restrict__ W, float* __restrict__ xw, int N) {
    int tid = blockIdx.x * blockDim.x + threadIdx.x;
    if (tid >= N * HID) return;
    int n = tid >> 5, f = tid & 31;
    const float* row = concat + (size_t)n * DLAT + off;
    float s = 0.f;
#pragma unroll
    for (int k = 0; k < HID; ++k) s += row[k] * W[k * HID + f];
    xw[tid] = s;
}

// CSR aggregate + self-loop + bias + tanh, write to concat column block col_off.
// 64 lanes per node: lane = 32*h + f; halves h=0/1 take alternating edges.
__global__ void agg32_kernel(const int* __restrict__ row_start, const int* __restrict__ csr_src,
                             const float* __restrict__ csr_norm, const float* __restrict__ xw,
                             const float* __restrict__ b, const float* __restrict__ dinv,
                             float* __restrict__ concat, int col_off, int N) {
    int tid = blockIdx.x * blockDim.x + threadIdx.x;
    int n = tid >> 6;
    if (n >= N) return;
    int lane = tid & 63;
    int h = lane >> 5, f = lane & 31;
    int beg = row_start[n], end = row_start[n + 1];
    float s = 0.f;
    for (int i = beg + h; i < end; i += 2) {
        int sn = csr_src[i];
        s += csr_norm[i] * xw[(size_t)sn * HID + f];
    }
    s += __shfl_xor(s, 32);
    if (h == 0) {
        float di = dinv[n];
        float tot = s + xw[(size_t)n * HID + f] * di * di + b[f];
        concat[(size_t)n * DLAT + col_off + f] = tanhf(tot);
    }
}

// ---- layer 4 (width 1) ----
__global__ void xw4_kernel(const float* __restrict__ concat, const float* __restrict__ W4,
                           float* __restrict__ xw4, int N) {
    int n = blockIdx.x * blockDim.x + threadIdx.x;
    if (n >= N) return;
    const float* row = concat + (size_t)n * DLAT + 64;
    float s = 0.f;
#pragma unroll
    for (int k = 0; k < HID; ++k) s += row[k] * W4[k];
    xw4[n] = s;
}

__global__ void agg1_kernel(const int* __restrict__ row_start, const int* __restrict__ csr_src,
                            const float* __restrict__ csr_norm, const float* __restrict__ xw4,
                            const float* __restrict__ b4, const float* __restrict__ dinv,
                            float* __restrict__ concat, int N) {
    int n = blockIdx.x * blockDim.x + threadIdx.x;
    if (n >= N) return;
    int beg = row_start[n], end = row_start[n + 1];
    float s = 0.f;
    for (int i = beg; i < end; ++i) s += csr_norm[i] * xw4[csr_src[i]];
    float di = dinv[n];
    concat[(size_t)n * DLAT + 96] = tanhf(s + xw4[n] * di * di + b4[0]);
}

// ---- top-k: stable rank (matches jnp.argsort(-v) tie-break: lower index first) ----
__global__ void topk_kernel(const float* __restrict__ concat, int* __restrict__ top_idx) {
    int g = blockIdx.x;
    int tid = threadIdx.x;
    __shared__ float v[NPG];
    if (tid < NPG) v[tid] = concat[(size_t)(g * NPG + tid) * DLAT + 96];
    __syncthreads();
    if (tid < NPG) {
        float vi = v[tid];
        int cnt = 0;
#pragma unroll 4
        for (int j = 0; j < NPG; ++j) {
            float vj = v[j];
            cnt += (vj > vi) || (vj == vi && j < tid);
        }
        if (cnt < TOPK) top_idx[g * TOPK + cnt] = g * NPG + tid;
    }
}

// ---- head: conv1(97->16 per slot) -> maxpool2 -> conv1d(16->32,k5) -> fc(352->128) -> fc(128->1)
__global__ __launch_bounds__(128) void head_kernel(
    const float* __restrict__ concat, const int* __restrict__ top_idx,
    const float* __restrict__ Wc1, const float* __restrict__ bc1,
    const float* __restrict__ Wc2, const float* __restrict__ bc2,
    const float* __restrict__ Wl1, const float* __restrict__ bl1,
    const float* __restrict__ Wl2, const float* __restrict__ bl2,
    float* __restrict__ out) {
    int g = blockIdx.x;
    int tid = threadIdx.x;  // 128 threads
    __shared__ float top[TOPK * DLAT];   // 2910
    __shared__ float y1[16 * TOPK];      // 480
    __shared__ float y2[16 * 15];        // 240
    __shared__ float y3[352];
    __shared__ float r[128];

    for (int idx = tid; idx < TOPK * DLAT; idx += 128) {
        int k = idx / DLAT, d = idx % DLAT;
        int node = top_idx[g * TOPK + k];
        top[idx] = concat[(size_t)node * DLAT + d];
    }
    __syncthreads();

    for (int idx = tid; idx < 16 * TOPK; idx += 128) {
        int c = idx / TOPK, k = idx % TOPK;
        float s = bc1[c];
        const float* w = Wc1 + c * DLAT;
        const float* t = top + k * DLAT;
#pragma unroll 4
        for (int d = 0; d < DLAT; ++d) s += t[d] * w[d];
        y1[c * TOPK + k] = fmaxf(s, 0.f);
    }
    __syncthreads();

    for (int idx = tid; idx < 16 * 15; idx += 128) {
        int c = idx / 15, j = idx % 15;
        y2[idx] = fmaxf(y1[c * TOPK + 2 * j], y1[c * TOPK + 2 * j + 1]);
    }
    __syncthreads();

    for (int idx = tid; idx < 352; idx += 128) {
        int o = idx / 11, t = idx % 11;
        float s = bc2[o];
#pragma unroll
        for (int i = 0; i < 16; ++i) {
#pragma unroll
            for (int k = 0; k < 5; ++k)
                s += Wc2[(o * 16 + i) * 5 + k] * y2[i * 15 + t + k];
        }
        y3[idx] = fmaxf(s, 0.f);
    }
    __syncthreads();

    {
        float s = bl1[tid];
        for (int d = 0; d < 352; ++d) s += y3[d] * Wl1[d * 128 + tid];
        r[tid] = fmaxf(s, 0.f) * Wl2[tid];
    }
    __syncthreads();
    if (tid < 64) r[tid] += r[tid + 64];
    __syncthreads();
    if (tid == 0) {
        float s = 0.f;
        for (int j = 0; j < 64; ++j) s += r[j];
        out[g] = s + bl2[0];
    }
}

// ---------------- launch ----------------

extern "C" void kernel_launch(void* const* d_in, const int* in_sizes, int n_in,
                              void* d_out, int out_size, void* d_ws, size_t ws_size,
                              hipStream_t stream) {
    const int* z = (const int*)d_in[0];
    const int* ei = (const int*)d_in[1];
    const float* ew = (const float*)d_in[3];
    const float* z_emb = (const float*)d_in[4];
    const float* Wg[4] = {(const float*)d_in[5], (const float*)d_in[7],
                          (const float*)d_in[9], (const float*)d_in[11]};
    const float* bg[4] = {(const float*)d_in[6], (const float*)d_in[8],
                          (const float*)d_in[10], (const float*)d_in[12]};
    const float* Wc1 = (const float*)d_in[13];
    const float* bc1 = (const float*)d_in[14];
    const float* Wc2 = (const float*)d_in[15];
    const float* bc2 = (const float*)d_in[16];
    const float* Wl1 = (const float*)d_in[17];
    const float* bl1 = (const float*)d_in[18];
    const float* Wl2 = (const float*)d_in[19];
    const float* bl2 = (const float*)d_in[20];
    float* out = (float*)d_out;

    const int N = in_sizes[0];
    const int E = in_sizes[1] / 2;
    const int G = out_size;  // 1000 graphs
    const int* src = ei;
    const int* dst = ei + E;

    // workspace layout
    char* ws = (char*)d_ws;
    float* dinv = (float*)ws;                 ws += sizeof(float) * N;
    int* cnt = (int*)ws;                      ws += sizeof(int) * N;
    int* exscan = (int*)ws;                   ws += sizeof(int) * N;
    int* bsum = (int*)ws;                     ws += sizeof(int) * 512;
    int* row_start = (int*)ws;                ws += sizeof(int) * (N + 1);
    int* cursor = (int*)ws;                   ws += sizeof(int) * N;
    int* csr_src = (int*)ws;                  ws += sizeof(int) * E;
    float* csr_norm = (float*)ws;             ws += sizeof(float) * E;
    float* xw = (float*)ws;                   ws += sizeof(float) * (size_t)N * HID;
    float* concat = (float*)ws;               ws += sizeof(float) * (size_t)N * DLAT;
    int* top_idx = (int*)ws;                  ws += sizeof(int) * G * TOPK;
    float* xw4 = xw;  // layer-4 reuses xw space

    const int B = 256;
    auto cdiv = [](long long a, long long b) { return (int)((a + b - 1) / b); };
    const int NB = cdiv(N, SCAN_B);

    // degree -> dinv
    zero_f<<<cdiv(N, B), B, 0, stream>>>(dinv, N);
    deg_kernel<<<cdiv(E, B), B, 0, stream>>>(dst, ew, dinv, E);
    dinv_kernel<<<cdiv(N, B), B, 0, stream>>>(dinv, N);

    // CSR build
    zero_i<<<cdiv(N, B), B, 0, stream>>>(cnt, N);
    count_kernel<<<cdiv(E, B), B, 0, stream>>>(dst, cnt, E);
    scanA_kernel<<<NB, SCAN_B, 0, stream>>>(cnt, exscan, bsum, N);
    scanB_kernel<<<1, 512, 0, stream>>>(bsum, NB);
    scanC_kernel<<<NB, SCAN_B, 0, stream>>>(exscan, bsum, row_start, cursor, N, E);
    fill_kernel<<<cdiv(E, B), B, 0, stream>>>(src, dst, ew, dinv, cursor, csr_src, csr_norm, E);

    // GCN layers 1-3 (32-wide), tanh fused, outputs into concat columns
    xw1_kernel<<<cdiv((long long)N * HID, B), B, 0, stream>>>(z, z_emb, Wg[0], xw, N);
    agg32_kernel<<<cdiv((long long)N * 64, B), B, 0, stream>>>(
        row_start, csr_src, csr_norm, xw, bg[0], dinv, concat, 0, N);
    for (int l = 1; l < 3; ++l) {
        xwl_kernel<<<cdiv((long long)N * HID, B), B, 0, stream>>>(
            concat, (l - 1) * HID, Wg[l], xw, N);
        agg32_kernel<<<cdiv((long long)N * 64, B), B, 0, stream>>>(
            row_start, csr_src, csr_norm, xw, bg[l], dinv, concat, l * HID, N);
    }

    // layer 4 (width 1) -> concat column 96
    xw4_kernel<<<cdiv(N, B), B, 0, stream>>>(concat, Wg[3], xw4, N);
    agg1_kernel<<<cdiv(N, B), B, 0, stream>>>(row_start, csr_src, csr_norm, xw4, bg[3], dinv, concat, N);

    // top-30 selection + CNN/MLP head
    topk_kernel<<<G, 128, 0, stream>>>(concat, top_idx);
    head_kernel<<<G, 128, 0, stream>>>(concat, top_idx, Wc1, bc1, Wc2, bc2,
                                       Wl1, bl1, Wl2, bl2, out);
}

// Round 3
// 733.408 us; speedup vs baseline: 1.5870x; 1.0767x over previous
//
#include <hip/hip_runtime.h>

#define HID 32
#define DLAT 97
#define NPG 100
#define TOPK 30
#define SCAN_B 256

// ---------------- helpers ----------------

__global__ void zero_i(int* p, int n) {
    int i = blockIdx.x * blockDim.x + threadIdx.x;
    if (i < n) p[i] = 0;
}

// ---------------- CSR build (counting sort by dst) ----------------

__global__ void count_kernel(const int* __restrict__ dst, int* __restrict__ cnt, int E) {
    int e = blockIdx.x * blockDim.x + threadIdx.x;
    if (e < E) atomicAdd(&cnt[dst[e]], 1);
}

// per-block exclusive scan of cnt -> exscan, block totals -> bsum
__global__ void scanA_kernel(const int* __restrict__ cnt, int* __restrict__ exscan,
                             int* __restrict__ bsum, int N) {
    __shared__ int sh[SCAN_B];
    int i = blockIdx.x * SCAN_B + threadIdx.x;
    int v = (i < N) ? cnt[i] : 0;
    sh[threadIdx.x] = v;
    __syncthreads();
    for (int off = 1; off < SCAN_B; off <<= 1) {
        int t = (threadIdx.x >= off) ? sh[threadIdx.x - off] : 0;
        __syncthreads();
        sh[threadIdx.x] += t;
        __syncthreads();
    }
    if (i < N) exscan[i] = sh[threadIdx.x] - v;  // exclusive
    if (threadIdx.x == SCAN_B - 1) bsum[blockIdx.x] = sh[threadIdx.x];
}

// single-block exclusive scan of bsum (NB <= 512)
__global__ void scanB_kernel(int* __restrict__ bsum, int NB) {
    __shared__ int sh[512];
    int v = (threadIdx.x < NB) ? bsum[threadIdx.x] : 0;
    sh[threadIdx.x] = v;
    __syncthreads();
    for (int off = 1; off < 512; off <<= 1) {
        int t = (threadIdx.x >= off) ? sh[threadIdx.x - off] : 0;
        __syncthreads();
        sh[threadIdx.x] += t;
        __syncthreads();
    }
    if (threadIdx.x < NB) bsum[threadIdx.x] = sh[threadIdx.x] - v;  // exclusive
}

// row_start = exscan + bsum[block]; cursor = copy; row_start[N] = E
__global__ void scanC_kernel(const int* __restrict__ exscan, const int* __restrict__ bsum,
                             int* __restrict__ row_start, int* __restrict__ cursor,
                             int N, int E) {
    int i = blockIdx.x * SCAN_B + threadIdx.x;
    if (i < N) {
        int v = exscan[i] + bsum[blockIdx.x];
        row_start[i] = v;
        cursor[i] = v;
    }
    if (i == 0) row_start[N] = E;
}

// fill CSR with packed {src, ew} — single 8B scattered store per edge
__global__ void fill_kernel(const int* __restrict__ src, const int* __restrict__ dst,
                            const float* __restrict__ ew, int* __restrict__ cursor,
                            int2* __restrict__ csr, int E) {
    int e = blockIdx.x * blockDim.x + threadIdx.x;
    if (e >= E) return;
    int d = dst[e];
    int slot = atomicAdd(&cursor[d], 1);
    csr[slot] = make_int2(src[e], __float_as_int(ew[e]));
}

// deg[n] = 1 + sum(ew over row) -> dinv[n]  (sequential CSR reads, no atomics)
__global__ void degdinv_kernel(const int* __restrict__ row_start, const int2* __restrict__ csr,
                               float* __restrict__ dinv, int N) {
    int n = blockIdx.x * blockDim.x + threadIdx.x;
    if (n >= N) return;
    int beg = row_start[n], end = row_start[n + 1];
    float s = 1.0f;
    for (int i = beg; i < end; ++i) s += __int_as_float(csr[i].y);
    dinv[n] = 1.0f / sqrtf(s);
}

// in-place: csr[i].ew *= dinv[src]  (the dinv[dst] factor is hoisted into agg)
__global__ void normfix_kernel(int2* __restrict__ csr, const float* __restrict__ dinv, int E) {
    int i = blockIdx.x * blockDim.x + threadIdx.x;
    if (i >= E) return;
    int2 v = csr[i];
    csr[i].y = __float_as_int(__int_as_float(v.y) * dinv[v.x]);
}

// ---------------- GCN layers ----------------

// layer 1: xw[n][f] = dot(z_emb[z[n]], W[:,f])
__global__ void xw1_kernel(const int* __restrict__ z, const float* __restrict__ z_emb,
                           const float* __restrict__ W, float* __restrict__ xw, int N) {
    int tid = blockIdx.x * blockDim.x + threadIdx.x;
    if (tid >= N * HID) return;
    int n = tid >> 5, f = tid & 31;
    const float* row = z_emb + (size_t)z[n] * HID;
    float s = 0.f;
#pragma unroll
    for (int k = 0; k < HID; ++k) s += row[k] * W[k * HID + f];
    xw[tid] = s;
}

// layers 2/3: input rows are concat[n*97 + off .. +32]
__global__ void xwl_kernel(const float* __restrict__ concat, int off,
                           const float* __restrict__ W, float* __restrict__ xw, int N) {
    int tid = blockIdx.x * blockDim.x + threadIdx.x;
    if (tid >= N * HID) return;
    int n = tid >> 5, f = tid & 31;
    const float* row = concat + (size_t)n * DLAT + off;
    float s = 0.f;
#pragma unroll
    for (int k = 0; k < HID; ++k) s += row[k] * W[k * HID + f];
    xw[tid] = s;
}

// CSR aggregate + self-loop + bias + tanh -> concat columns [col_off, col_off+32)
// 64 lanes per node: lane = 32*h + f; halves h=0/1 take alternating edges.
// out = dinv[n]*sum(a_i*xw[src_i]) + xw[n]*dinv[n]^2 + b
__global__ void agg32_kernel(const int* __restrict__ row_start, const int2* __restrict__ csr,
                             const float* __restrict__ xw, const float* __restrict__ b,
                             const float* __restrict__ dinv,
                             float* __restrict__ concat, int col_off, int N) {
    int tid = blockIdx.x * blockDim.x + threadIdx.x;
    int n = tid >> 6;
    if (n >= N) return;
    int lane = tid & 63;
    int h = lane >> 5, f = lane & 31;
    int beg = row_start[n], end = row_start[n + 1];
    float s = 0.f;
    for (int i = beg + h; i < end; i += 2) {
        int2 v = csr[i];
        s += __int_as_float(v.y) * xw[(size_t)v.x * HID + f];
    }
    s += __shfl_xor(s, 32);
    if (h == 0) {
        float di = dinv[n];
        float tot = s * di + xw[(size_t)n * HID + f] * di * di + b[f];
        concat[(size_t)n * DLAT + col_off + f] = tanhf(tot);
    }
}

// ---- layer 4 (width 1) ----
__global__ void xw4_kernel(const float* __restrict__ concat, const float* __restrict__ W4,
                           float* __restrict__ xw4, int N) {
    int n = blockIdx.x * blockDim.x + threadIdx.x;
    if (n >= N) return;
    const float* row = concat + (size_t)n * DLAT + 64;
    float s = 0.f;
#pragma unroll
    for (int k = 0; k < HID; ++k) s += row[k] * W4[k];
    xw4[n] = s;
}

__global__ void agg1_kernel(const int* __restrict__ row_start, const int2* __restrict__ csr,
                            const float* __restrict__ xw4, const float* __restrict__ b4,
                            const float* __restrict__ dinv, float* __restrict__ concat, int N) {
    int n = blockIdx.x * blockDim.x + threadIdx.x;
    if (n >= N) return;
    int beg = row_start[n], end = row_start[n + 1];
    float s = 0.f;
    for (int i = beg; i < end; ++i) {
        int2 v = csr[i];
        s += __int_as_float(v.y) * xw4[v.x];
    }
    float di = dinv[n];
    concat[(size_t)n * DLAT + 96] = tanhf(s * di + xw4[n] * di * di + b4[0]);
}

// ---- top-k: stable rank (matches jnp.argsort(-v) tie-break: lower index first) ----
__global__ void topk_kernel(const float* __restrict__ concat, int* __restrict__ top_idx) {
    int g = blockIdx.x;
    int tid = threadIdx.x;
    __shared__ float v[NPG];
    if (tid < NPG) v[tid] = concat[(size_t)(g * NPG + tid) * DLAT + 96];
    __syncthreads();
    if (tid < NPG) {
        float vi = v[tid];
        int cnt = 0;
#pragma unroll 4
        for (int j = 0; j < NPG; ++j) {
            float vj = v[j];
            cnt += (vj > vi) || (vj == vi && j < tid);
        }
        if (cnt < TOPK) top_idx[g * TOPK + cnt] = g * NPG + tid;
    }
}

// ---- head: conv1(97->16 per slot) -> maxpool2 -> conv1d(16->32,k5) -> fc(352->128) -> fc(128->1)
__global__ __launch_bounds__(128) void head_kernel(
    const float* __restrict__ concat, const int* __restrict__ top_idx,
    const float* __restrict__ Wc1, const float* __restrict__ bc1,
    const float* __restrict__ Wc2, const float* __restrict__ bc2,
    const float* __restrict__ Wl1, const float* __restrict__ bl1,
    const float* __restrict__ Wl2, const float* __restrict__ bl2,
    float* __restrict__ out) {
    int g = blockIdx.x;
    int tid = threadIdx.x;  // 128 threads
    __shared__ float top[TOPK * DLAT];   // 2910
    __shared__ float y1[16 * TOPK];      // 480
    __shared__ float y2[16 * 15];        // 240
    __shared__ float y3[352];
    __shared__ float r[128];

    for (int idx = tid; idx < TOPK * DLAT; idx += 128) {
        int k = idx / DLAT, d = idx % DLAT;
        int node = top_idx[g * TOPK + k];
        top[idx] = concat[(size_t)node * DLAT + d];
    }
    __syncthreads();

    for (int idx = tid; idx < 16 * TOPK; idx += 128) {
        int c = idx / TOPK, k = idx % TOPK;
        float s = bc1[c];
        const float* w = Wc1 + c * DLAT;
        const float* t = top + k * DLAT;
#pragma unroll 4
        for (int d = 0; d < DLAT; ++d) s += t[d] * w[d];
        y1[c * TOPK + k] = fmaxf(s, 0.f);
    }
    __syncthreads();

    for (int idx = tid; idx < 16 * 15; idx += 128) {
        int c = idx / 15, j = idx % 15;
        y2[idx] = fmaxf(y1[c * TOPK + 2 * j], y1[c * TOPK + 2 * j + 1]);
    }
    __syncthreads();

    for (int idx = tid; idx < 352; idx += 128) {
        int o = idx / 11, t = idx % 11;
        float s = bc2[o];
#pragma unroll
        for (int i = 0; i < 16; ++i) {
#pragma unroll
            for (int k = 0; k < 5; ++k)
                s += Wc2[(o * 16 + i) * 5 + k] * y2[i * 15 + t + k];
        }
        y3[idx] = fmaxf(s, 0.f);
    }
    __syncthreads();

    {
        float s = bl1[tid];
        for (int d = 0; d < 352; ++d) s += y3[d] * Wl1[d * 128 + tid];
        r[tid] = fmaxf(s, 0.f) * Wl2[tid];
    }
    __syncthreads();
    if (tid < 64) r[tid] += r[tid + 64];
    __syncthreads();
    if (tid == 0) {
        float s = 0.f;
        for (int j = 0; j < 64; ++j) s += r[j];
        out[g] = s + bl2[0];
    }
}

// ---------------- launch ----------------

extern "C" void kernel_launch(void* const* d_in, const int* in_sizes, int n_in,
                              void* d_out, int out_size, void* d_ws, size_t ws_size,
                              hipStream_t stream) {
    const int* z = (const int*)d_in[0];
    const int* ei = (const int*)d_in[1];
    const float* ew = (const float*)d_in[3];
    const float* z_emb = (const float*)d_in[4];
    const float* Wg[4] = {(const float*)d_in[5], (const float*)d_in[7],
                          (const float*)d_in[9], (const float*)d_in[11]};
    const float* bg[4] = {(const float*)d_in[6], (const float*)d_in[8],
                          (const float*)d_in[10], (const float*)d_in[12]};
    const float* Wc1 = (const float*)d_in[13];
    const float* bc1 = (const float*)d_in[14];
    const float* Wc2 = (const float*)d_in[15];
    const float* bc2 = (const float*)d_in[16];
    const float* Wl1 = (const float*)d_in[17];
    const float* bl1 = (const float*)d_in[18];
    const float* Wl2 = (const float*)d_in[19];
    const float* bl2 = (const float*)d_in[20];
    float* out = (float*)d_out;

    const int N = in_sizes[0];
    const int E = in_sizes[1] / 2;
    const int G = out_size;  // 1000 graphs
    const int* src = ei;
    const int* dst = ei + E;

    // workspace layout
    char* ws = (char*)d_ws;
    float* dinv = (float*)ws;                 ws += sizeof(float) * N;
    int* cnt = (int*)ws;                      ws += sizeof(int) * N;
    int* exscan = (int*)ws;                   ws += sizeof(int) * N;
    int* bsum = (int*)ws;                     ws += sizeof(int) * 512;
    int* row_start = (int*)ws;                ws += sizeof(int) * (N + 1);
    int* cursor = (int*)ws;                   ws += sizeof(int) * N;
    ws = (char*)(((uintptr_t)ws + 15) & ~(uintptr_t)15);
    int2* csr = (int2*)ws;                    ws += sizeof(int2) * (size_t)E;
    float* xw = (float*)ws;                   ws += sizeof(float) * (size_t)N * HID;
    float* concat = (float*)ws;               ws += sizeof(float) * (size_t)N * DLAT;
    int* top_idx = (int*)ws;                  ws += sizeof(int) * G * TOPK;
    float* xw4 = xw;  // layer-4 reuses xw space

    const int B = 256;
    auto cdiv = [](long long a, long long b) { return (int)((a + b - 1) / b); };
    const int NB = cdiv(N, SCAN_B);

    // CSR build (counting sort by dst), packed {src, ew}
    zero_i<<<cdiv(N, B), B, 0, stream>>>(cnt, N);
    count_kernel<<<cdiv(E, B), B, 0, stream>>>(dst, cnt, E);
    scanA_kernel<<<NB, SCAN_B, 0, stream>>>(cnt, exscan, bsum, N);
    scanB_kernel<<<1, 512, 0, stream>>>(bsum, NB);
    scanC_kernel<<<NB, SCAN_B, 0, stream>>>(exscan, bsum, row_start, cursor, N, E);
    fill_kernel<<<cdiv(E, B), B, 0, stream>>>(src, dst, ew, cursor, csr, E);

    // degree/dinv from CSR (sequential, no atomics), then fold dinv[src] into csr ew
    degdinv_kernel<<<cdiv(N, B), B, 0, stream>>>(row_start, csr, dinv, N);
    normfix_kernel<<<cdiv(E, B), B, 0, stream>>>(csr, dinv, E);

    // GCN layers 1-3 (32-wide), tanh fused, outputs into concat columns
    xw1_kernel<<<cdiv((long long)N * HID, B), B, 0, stream>>>(z, z_emb, Wg[0], xw, N);
    agg32_kernel<<<cdiv((long long)N * 64, B), B, 0, stream>>>(
        row_start, csr, xw, bg[0], dinv, concat, 0, N);
    for (int l = 1; l < 3; ++l) {
        xwl_kernel<<<cdiv((long long)N * HID, B), B, 0, stream>>>(
            concat, (l - 1) * HID, Wg[l], xw, N);
        agg32_kernel<<<cdiv((long long)N * 64, B), B, 0, stream>>>(
            row_start, csr, xw, bg[l], dinv, concat, l * HID, N);
    }

    // layer 4 (width 1) -> concat column 96
    xw4_kernel<<<cdiv(N, B), B, 0, stream>>>(concat, Wg[3], xw4, N);
    agg1_kernel<<<cdiv(N, B), B, 0, stream>>>(row_start, csr, xw4, bg[3], dinv, concat, N);

    // top-30 selection + CNN/MLP head
    topk_kernel<<<G, 128, 0, stream>>>(concat, top_idx);
    head_kernel<<<G, 128, 0, stream>>>(concat, top_idx, Wc1, bc1, Wc2, bc2,
                                       Wl1, bl1, Wl2, bl2, out);
}